// Round 2
// baseline (1121.082 us; speedup 1.0000x reference)
//
#include <hip/hip_runtime.h>

// Problem: B=4, T=2048, D_MODEL=2048, H=16, KV=8, HD=128, G=2.
// Storage dtype: float32 in/out (reference dtypes). Compare is bf16-lenient
// (2% of absmax). Internal compute: bf16 MFMA with fp32 accumulation.

typedef unsigned short u16;
typedef unsigned int u32;
typedef __attribute__((ext_vector_type(8))) short bf16x8;   // 8 bf16 in 4 VGPRs
typedef __attribute__((ext_vector_type(4))) float f32x4;

__device__ __forceinline__ float bf2f(u16 v) {
    union { u32 u; float f; } x; x.u = ((u32)v) << 16; return x.f;
}
__device__ __forceinline__ u16 f2bf(float f) {
    union { float f; u32 u; } x; x.f = f;
    u32 u = x.u;
    return (u16)((u + 0x7FFFu + ((u >> 16) & 1u)) >> 16);  // RNE; finite inputs
}
__device__ __forceinline__ f32x4 mfma_bf16(bf16x8 a, bf16x8 b, f32x4 c) {
    return __builtin_amdgcn_mfma_f32_16x16x32_bf16(a, b, c, 0, 0, 0);
}

// ---------------------------------------------------------------------------
// Transpose + cast f32 -> bf16: in[R][C] f32 -> out[C][R] bf16.
// Grid (C/32, R/32), block 256.
// ---------------------------------------------------------------------------
__global__ __launch_bounds__(256)
void transpose_f2b(const float* __restrict__ in, u16* __restrict__ out, int R, int C) {
    __shared__ float tile[32][33];
    const int tx = threadIdx.x & 31, ty = threadIdx.x >> 5;
    const long c0 = (long)blockIdx.x * 32, r0 = (long)blockIdx.y * 32;
#pragma unroll
    for (int i = 0; i < 4; i++) {
        int r = ty + i * 8;
        tile[r][tx] = in[(r0 + r) * C + c0 + tx];
    }
    __syncthreads();
#pragma unroll
    for (int i = 0; i < 4; i++) {
        int c = ty + i * 8;
        out[(c0 + c) * R + r0 + tx] = f2bf(tile[tx][c]);
    }
}

// ---------------------------------------------------------------------------
// Straight cast f32 -> bf16, 8 elements/thread.
// ---------------------------------------------------------------------------
__global__ __launch_bounds__(256)
void cast_f2b(const float* __restrict__ in, u16* __restrict__ out) {
    const long i = ((long)blockIdx.x * 256 + threadIdx.x) * 8;
    float4 a = *(const float4*)(in + i);
    float4 b = *(const float4*)(in + i + 4);
    bf16x8 v;
    v[0] = (short)f2bf(a.x); v[1] = (short)f2bf(a.y);
    v[2] = (short)f2bf(a.z); v[3] = (short)f2bf(a.w);
    v[4] = (short)f2bf(b.x); v[5] = (short)f2bf(b.y);
    v[6] = (short)f2bf(b.z); v[7] = (short)f2bf(b.w);
    *(bf16x8*)(out + i) = v;
}

// ---------------------------------------------------------------------------
// GEMM: C[M][N] = A[M][K] @ Bt[N][K]^T, bf16 in, fp32 accum.
// Tile 128x128, BK=32. 4 waves, each 64x64 (4x4 blocks of 16x16x32 MFMA).
// C/D layout: col=lane&15, row=(lane>>4)*4+reg (HW-verified).
// F32OUT selects f32 vs bf16 output.
// ---------------------------------------------------------------------------
template <bool F32OUT>
__global__ __launch_bounds__(256)
void gemm_bt_bf16(const u16* __restrict__ A, const u16* __restrict__ Bt,
                  void* __restrict__ Cp, int M, int N, int K) {
    __shared__ u16 As[128][40];   // +8 pad: 16B-aligned rows, breaks pow2 stride
    __shared__ u16 Bs[128][40];
    const int tid = threadIdx.x;
    const int wid = tid >> 6, lane = tid & 63;
    const int q4 = lane >> 4, n16 = lane & 15;
    const int wr = (wid >> 1) * 64, wc = (wid & 1) * 64;
    const long rowT = (long)blockIdx.y * 128, colT = (long)blockIdx.x * 128;

    const int lr = tid >> 2;          // 0..63
    const int lc = (tid & 3) * 8;     // 0,8,16,24
    const u16* Ag  = A  + (rowT + lr) * K + lc;
    const u16* Ag2 = Ag + (long)64 * K;
    const u16* Bg  = Bt + (colT + lr) * K + lc;
    const u16* Bg2 = Bg + (long)64 * K;

    f32x4 acc[4][4];
#pragma unroll
    for (int i = 0; i < 4; i++)
#pragma unroll
        for (int j = 0; j < 4; j++) acc[i][j] = (f32x4){0.f, 0.f, 0.f, 0.f};

    for (int k0 = 0; k0 < K; k0 += 32) {
        __syncthreads();
        *(bf16x8*)&As[lr][lc]      = *(const bf16x8*)(Ag + k0);
        *(bf16x8*)&As[lr + 64][lc] = *(const bf16x8*)(Ag2 + k0);
        *(bf16x8*)&Bs[lr][lc]      = *(const bf16x8*)(Bg + k0);
        *(bf16x8*)&Bs[lr + 64][lc] = *(const bf16x8*)(Bg2 + k0);
        __syncthreads();
        bf16x8 af[4], bfr[4];
#pragma unroll
        for (int mb = 0; mb < 4; mb++) af[mb]  = *(const bf16x8*)&As[wr + mb * 16 + n16][q4 * 8];
#pragma unroll
        for (int nb = 0; nb < 4; nb++) bfr[nb] = *(const bf16x8*)&Bs[wc + nb * 16 + n16][q4 * 8];
#pragma unroll
        for (int mb = 0; mb < 4; mb++)
#pragma unroll
            for (int nb = 0; nb < 4; nb++)
                acc[mb][nb] = mfma_bf16(af[mb], bfr[nb], acc[mb][nb]);
    }

#pragma unroll
    for (int mb = 0; mb < 4; mb++)
#pragma unroll
        for (int nb = 0; nb < 4; nb++)
#pragma unroll
            for (int r = 0; r < 4; r++) {
                long row = rowT + wr + mb * 16 + q4 * 4 + r;
                long col = colT + wc + nb * 16 + n16;
                if (F32OUT) ((float*)Cp)[row * N + col] = acc[mb][nb][r];
                else        ((u16*)Cp)[row * N + col]   = f2bf(acc[mb][nb][r]);
            }
}

// ---------------------------------------------------------------------------
// RMSNorm + interleaved RoPE, in-place on bf16 qkv buffer [8192][4096].
// One wave per head-vector (24/token: 16 q + 8 k). Lane owns pair (2i,2i+1).
// cos/sin/gamma are f32.
// ---------------------------------------------------------------------------
__global__ __launch_bounds__(256)
void rmsnorm_rope(u16* __restrict__ qkv, const float* __restrict__ cosT,
                  const float* __restrict__ sinT, const float* __restrict__ qg,
                  const float* __restrict__ kg) {
    const int w = blockIdx.x * 4 + (threadIdx.x >> 6);
    const int lane = threadIdx.x & 63;
    const int token = w / 24;                 // 0..8191 (= b*T + t)
    const int hv = w - token * 24;            // 0..15 q-head, 16..23 k-head
    const long base = (long)token * 4096 + (hv < 16 ? hv * 128 : 2048 + (hv - 16) * 128);
    const float* g = (hv < 16) ? qg : kg;
    const int t = token & 2047;

    u32 pair = *(const u32*)(qkv + base + 2 * lane);
    float a0 = bf2f((u16)(pair & 0xffffu));
    float a1 = bf2f((u16)(pair >> 16));
    float ss = a0 * a0 + a1 * a1;
#pragma unroll
    for (int off = 32; off > 0; off >>= 1) ss += __shfl_xor(ss, off);
    float rs = rsqrtf(ss * (1.0f / 128.0f) + 1e-6f);
    float h0 = a0 * rs * g[2 * lane];
    float h1 = a1 * rs * g[2 * lane + 1];
    float2 cp = *(const float2*)(cosT + (long)t * 128 + 2 * lane);
    float2 sp = *(const float2*)(sinT + (long)t * 128 + 2 * lane);
    float o0 = h0 * cp.x - h1 * sp.x;      // out[2i]   = h[2i]c - h[2i+1]s
    float o1 = h1 * cp.y + h0 * sp.y;      // out[2i+1] = h[2i+1]c + h[2i]s
    *(u32*)(qkv + base + 2 * lane) = ((u32)f2bf(o0)) | (((u32)f2bf(o1)) << 16);
}

// ---------------------------------------------------------------------------
// Flash attention (non-causal, GQA G=2). Grid (T/128, B*H), block 256.
// WG: 128 Q-rows of one (b,h); wave w owns rows w*32..w*32+31 (2 m-blocks).
// K-tile = 32 keys. S via MFMA (K-tile in LDS), online softmax in regs,
// P -> per-wave LDS (C-layout -> A-layout), PV via MFMA with V^T in LDS.
// ---------------------------------------------------------------------------
__global__ __launch_bounds__(256)
void flash_attn(const u16* __restrict__ qkv, u16* __restrict__ attn) {
    __shared__ u16 Ks[32][136];       // [key][d], pad 128->136 (16B-aligned rows)
    __shared__ u16 Vt[128][40];       // [d][key], pad 32->40
    __shared__ u16 Ps[4][32][40];     // per-wave P tile [row][key]
    const int tid = threadIdx.x, wid = tid >> 6, lane = tid & 63;
    const int q4 = lane >> 4, n16 = lane & 15;
    const int b = blockIdx.y >> 4, h = blockIdx.y & 15;
    const int kvh = h >> 1;
    const long qtile = (long)blockIdx.x * 128;
    const long rowbase = (long)b * 2048;

    bf16x8 qf[2][4];
#pragma unroll
    for (int mb = 0; mb < 2; mb++) {
        const u16* p = qkv + (rowbase + qtile + wid * 32 + mb * 16 + n16) * 4096 + h * 128;
#pragma unroll
        for (int c = 0; c < 4; c++) qf[mb][c] = *(const bf16x8*)(p + c * 32 + q4 * 8);
    }

    f32x4 o[2][8];
#pragma unroll
    for (int i = 0; i < 2; i++)
#pragma unroll
        for (int j = 0; j < 8; j++) o[i][j] = (f32x4){0.f, 0.f, 0.f, 0.f};
    float m_i[2][4], l_i[2][4];
#pragma unroll
    for (int i = 0; i < 2; i++)
#pragma unroll
        for (int r = 0; r < 4; r++) { m_i[i][r] = -1e30f; l_i[i][r] = 0.f; }

    const int skey = tid >> 3;          // 0..31
    const int sd = (tid & 7) * 16;      // 0..112
    const float scale = 0.08838834764831845f;   // 1/sqrt(128)

    for (int kt = 0; kt < 2048; kt += 32) {
        __syncthreads();
        const u16* kgp = qkv + (rowbase + kt + skey) * 4096 + 2048 + kvh * 128 + sd;
        *(bf16x8*)&Ks[skey][sd]     = *(const bf16x8*)kgp;
        *(bf16x8*)&Ks[skey][sd + 8] = *(const bf16x8*)(kgp + 8);
        const u16* vgp = qkv + (rowbase + kt + skey) * 4096 + 3072 + kvh * 128 + sd;
        bf16x8 v0 = *(const bf16x8*)vgp;
        bf16x8 v1 = *(const bf16x8*)(vgp + 8);
#pragma unroll
        for (int j = 0; j < 8; j++) {
            Vt[sd + j][skey]     = (u16)v0[j];
            Vt[sd + 8 + j][skey] = (u16)v1[j];
        }
        __syncthreads();

        // S = Q K^T
        f32x4 s[2][2];
#pragma unroll
        for (int i = 0; i < 2; i++)
#pragma unroll
            for (int j = 0; j < 2; j++) s[i][j] = (f32x4){0.f, 0.f, 0.f, 0.f};
#pragma unroll
        for (int c = 0; c < 4; c++) {
            bf16x8 b0 = *(const bf16x8*)&Ks[n16][c * 32 + q4 * 8];
            bf16x8 b1 = *(const bf16x8*)&Ks[16 + n16][c * 32 + q4 * 8];
            s[0][0] = mfma_bf16(qf[0][c], b0, s[0][0]);
            s[0][1] = mfma_bf16(qf[0][c], b1, s[0][1]);
            s[1][0] = mfma_bf16(qf[1][c], b0, s[1][0]);
            s[1][1] = mfma_bf16(qf[1][c], b1, s[1][1]);
        }

        // online softmax (rows in lane quads; reduce across the 16 col-lanes)
        float p[2][2][4];
#pragma unroll
        for (int mb = 0; mb < 2; mb++) {
#pragma unroll
            for (int r = 0; r < 4; r++) {
                float v0s = s[mb][0][r] * scale;
                float v1s = s[mb][1][r] * scale;
                float rm = fmaxf(v0s, v1s);
#pragma unroll
                for (int off = 1; off < 16; off <<= 1)
                    rm = fmaxf(rm, __shfl_xor(rm, off));
                float mnew = fmaxf(m_i[mb][r], rm);
                float alpha = __expf(m_i[mb][r] - mnew);
                m_i[mb][r] = mnew;
                float p0 = __expf(v0s - mnew);
                float p1 = __expf(v1s - mnew);
                p[mb][0][r] = p0; p[mb][1][r] = p1;
                float rsum = p0 + p1;
#pragma unroll
                for (int off = 1; off < 16; off <<= 1)
                    rsum += __shfl_xor(rsum, off);
                l_i[mb][r] = l_i[mb][r] * alpha + rsum;
#pragma unroll
                for (int nbh = 0; nbh < 8; nbh++) o[mb][nbh][r] *= alpha;
            }
        }

        // P: C-layout regs -> LDS -> A-layout frags
#pragma unroll
        for (int mb = 0; mb < 2; mb++)
#pragma unroll
            for (int nb = 0; nb < 2; nb++)
#pragma unroll
                for (int r = 0; r < 4; r++)
                    Ps[wid][mb * 16 + q4 * 4 + r][nb * 16 + n16] = f2bf(p[mb][nb][r]);
        __syncthreads();
        bf16x8 pf0 = *(const bf16x8*)&Ps[wid][n16][q4 * 8];
        bf16x8 pf1 = *(const bf16x8*)&Ps[wid][16 + n16][q4 * 8];
#pragma unroll
        for (int nbh = 0; nbh < 8; nbh++) {
            bf16x8 vf = *(const bf16x8*)&Vt[nbh * 16 + n16][q4 * 8];
            o[0][nbh] = mfma_bf16(pf0, vf, o[0][nbh]);
            o[1][nbh] = mfma_bf16(pf1, vf, o[1][nbh]);
        }
    }

    // epilogue: O /= l, write bf16 [8192][2048] at col h*128+d
#pragma unroll
    for (int mb = 0; mb < 2; mb++)
#pragma unroll
        for (int r = 0; r < 4; r++) {
            float inv = 1.0f / l_i[mb][r];
            long row = rowbase + qtile + wid * 32 + mb * 16 + q4 * 4 + r;
            u16* op = attn + row * 2048 + h * 128 + n16;
#pragma unroll
            for (int nbh = 0; nbh < 8; nbh++)
                op[nbh * 16] = f2bf(o[mb][nbh][r] * inv);
        }
}

// ---------------------------------------------------------------------------
// Host launch. ws layout (bytes), total 120 MB:
//   Bt_qkv bf16 [4096][2048] @ 0          (16,777,216)
//   Bt_o   bf16 [2048][2048] @ 16777216   ( 8,388,608)
//   xb/attn bf16 [8192][2048] @ 25165824  (33,554,432)  (xb dead after gemm1)
//   qkv    bf16 [8192][4096] @ 58720256   (67,108,864)
// ---------------------------------------------------------------------------
extern "C" void kernel_launch(void* const* d_in, const int* in_sizes, int n_in,
                              void* d_out, int out_size, void* d_ws, size_t ws_size,
                              hipStream_t stream) {
    const float* x    = (const float*)d_in[0];
    const float* cosT = (const float*)d_in[1];
    const float* sinT = (const float*)d_in[2];
    const float* Wq   = (const float*)d_in[3];
    const float* Wk   = (const float*)d_in[4];
    const float* Wv   = (const float*)d_in[5];
    const float* Wo   = (const float*)d_in[6];
    const float* qg   = (const float*)d_in[7];
    const float* kg   = (const float*)d_in[8];
    float* out = (float*)d_out;

    char* ws = (char*)d_ws;
    u16* Bt_qkv = (u16*)(ws);
    u16* Bt_o   = (u16*)(ws + 16777216);
    u16* xb     = (u16*)(ws + 25165824);
    u16* attn   = (u16*)(ws + 25165824);   // reuses xb after gemm1
    u16* qkv    = (u16*)(ws + 58720256);

    // Weight transposes + cast: W[K][N] f32 -> Bt[N][K] bf16
    transpose_f2b<<<dim3(64, 64), 256, 0, stream>>>(Wq, Bt_qkv, 2048, 2048);
    transpose_f2b<<<dim3(32, 64), 256, 0, stream>>>(Wk, Bt_qkv + (size_t)2048 * 2048, 2048, 1024);
    transpose_f2b<<<dim3(32, 64), 256, 0, stream>>>(Wv, Bt_qkv + (size_t)3072 * 2048, 2048, 1024);
    transpose_f2b<<<dim3(64, 64), 256, 0, stream>>>(Wo, Bt_o, 2048, 2048);

    // x f32 -> bf16
    cast_f2b<<<dim3(8192), 256, 0, stream>>>(x, xb);

    // qkv = x @ [Wq|Wk|Wv]  (bf16 out)
    gemm_bt_bf16<false><<<dim3(32, 64), 256, 0, stream>>>(xb, Bt_qkv, qkv, 8192, 4096, 2048);

    // RMSNorm + RoPE in place (q and k heads)
    rmsnorm_rope<<<dim3(49152), 256, 0, stream>>>(qkv, cosT, sinT, qg, kg);

    // attention (bf16 out into attn, overwriting xb which is now dead)
    flash_attn<<<dim3(16, 64), 256, 0, stream>>>(qkv, attn);

    // out = attn @ Wo  (f32 out)
    gemm_bt_bf16<true><<<dim3(16, 64), 256, 0, stream>>>(attn, Bt_o, out, 8192, 2048, 2048);
}

// Round 3
// 922.026 us; speedup vs baseline: 1.2159x; 1.2159x over previous
//
#include <hip/hip_runtime.h>

// B=4, T=2048, D_MODEL=2048, H=16, KV=8, HD=128, G=2. f32 storage in/out,
// bf16 MFMA internals, fp32 accum. Compare threshold is bf16-lenient.

typedef unsigned short u16;
typedef unsigned int u32;
typedef __attribute__((ext_vector_type(8))) short bf16x8;
typedef __attribute__((ext_vector_type(4))) float f32x4;

__device__ __forceinline__ float bf2f(u16 v) {
    union { u32 u; float f; } x; x.u = ((u32)v) << 16; return x.f;
}
__device__ __forceinline__ u16 f2bf(float f) {
    union { float f; u32 u; } x; x.f = f;
    u32 u = x.u;
    return (u16)((u + 0x7FFFu + ((u >> 16) & 1u)) >> 16);  // RNE
}
// truncating pack of two f32 -> two bf16 (hot loop only; p in [0,1])
__device__ __forceinline__ u32 packtrunc(float a, float b) {
    union { float f; u32 u; } x, y; x.f = a; y.f = b;
    return (x.u >> 16) | (y.u & 0xffff0000u);
}
__device__ __forceinline__ f32x4 mfma_bf16(bf16x8 a, bf16x8 b, f32x4 c) {
    return __builtin_amdgcn_mfma_f32_16x16x32_bf16(a, b, c, 0, 0, 0);
}
// async global->LDS, 16B per lane; LDS dest = wave-uniform base + lane*16
__device__ __forceinline__ void gl_lds16(const u16* g, u16* l) {
    __builtin_amdgcn_global_load_lds((const __attribute__((address_space(1))) void*)g,
                                     (__attribute__((address_space(3))) void*)l, 16, 0, 0);
}

// ---------------------------------------------------------------------------
// Transpose + cast f32 -> bf16: in[R][C] f32 -> out[C][R] bf16.
// ---------------------------------------------------------------------------
__global__ __launch_bounds__(256)
void transpose_f2b(const float* __restrict__ in, u16* __restrict__ out, int R, int C) {
    __shared__ float tile[32][33];
    const int tx = threadIdx.x & 31, ty = threadIdx.x >> 5;
    const long c0 = (long)blockIdx.x * 32, r0 = (long)blockIdx.y * 32;
#pragma unroll
    for (int i = 0; i < 4; i++)
        tile[ty + i * 8][tx] = in[(r0 + ty + i * 8) * C + c0 + tx];
    __syncthreads();
#pragma unroll
    for (int i = 0; i < 4; i++)
        out[(c0 + ty + i * 8) * R + r0 + tx] = f2bf(tile[tx][ty + i * 8]);
}

// ---------------------------------------------------------------------------
// Straight cast f32 -> bf16, 8 elem/thread.
// ---------------------------------------------------------------------------
__global__ __launch_bounds__(256)
void cast_f2b(const float* __restrict__ in, u16* __restrict__ out) {
    const long i = ((long)blockIdx.x * 256 + threadIdx.x) * 8;
    float4 a = *(const float4*)(in + i);
    float4 b = *(const float4*)(in + i + 4);
    bf16x8 v;
    v[0] = (short)f2bf(a.x); v[1] = (short)f2bf(a.y);
    v[2] = (short)f2bf(a.z); v[3] = (short)f2bf(a.w);
    v[4] = (short)f2bf(b.x); v[5] = (short)f2bf(b.y);
    v[6] = (short)f2bf(b.z); v[7] = (short)f2bf(b.w);
    *(bf16x8*)(out + i) = v;
}

// ---------------------------------------------------------------------------
// bf16 transpose of the V slice of qkv: qkv[token][3072 + d'] -> Vt[b][d'][t]
// Vt row index = b*1024 + d' (d' = kvh*128 + d), col = t in [0,2048).
// Grid (32, 256).
// ---------------------------------------------------------------------------
__global__ __launch_bounds__(256)
void transpose_v(const u16* __restrict__ qkv, u16* __restrict__ Vt) {
    __shared__ u16 tile[32][33];
    const int tx = threadIdx.x & 31, ty = threadIdx.x >> 5;
    const int d0 = blockIdx.x * 32;
    const int tok0 = blockIdx.y * 32;
#pragma unroll
    for (int i = 0; i < 4; i++)
        tile[ty + i * 8][tx] = qkv[(long)(tok0 + ty + i * 8) * 4096 + 3072 + d0 + tx];
    __syncthreads();
    const int b = tok0 >> 11;
    const long orow = (long)b * 1024 + d0;
    const int t0 = tok0 & 2047;
#pragma unroll
    for (int i = 0; i < 4; i++)
        Vt[(orow + ty + i * 8) * 2048 + t0 + tx] = tile[tx][ty + i * 8];
}

// ---------------------------------------------------------------------------
// GEMM (m97 structure): C[M][N] = A[M][K] @ Bt[N][K]^T, bf16, fp32 accum.
// 128x128 tile, BK=32, flat LDS, global_load_lds width-16 staging.
// ---------------------------------------------------------------------------
template <bool F32OUT>
__global__ __launch_bounds__(256)
void gemm_bt_bf16(const u16* __restrict__ A, const u16* __restrict__ Bt,
                  void* __restrict__ Cp, int M, int N, int K) {
    __shared__ __align__(16) u16 As[128 * 32];
    __shared__ __align__(16) u16 Bs[128 * 32];
    const int tid = threadIdx.x, wid = tid >> 6, lane = tid & 63;
    const int q4 = lane >> 4, n16 = lane & 15;
    const int wr = (wid >> 1) * 64, wc = (wid & 1) * 64;
    const long rowT = (long)blockIdx.y * 128, colT = (long)blockIdx.x * 128;

    // staging map: wave w covers tile rows [w*32, w*32+32); lane l -> row w*32 + l/4
    // (+16 for second call), col (l%4)*8. LDS flat offset = w*1024 + l*8 (+512).
    const int srow = wid * 32 + (lane >> 2);
    const int scol = (lane & 3) * 8;
    const u16* Ag0 = A + (rowT + srow) * K + scol;
    const u16* Ag1 = Ag0 + (long)16 * K;
    const u16* Bg0 = Bt + (colT + srow) * K + scol;
    const u16* Bg1 = Bg0 + (long)16 * K;
    u16* la0 = As + wid * 1024 + lane * 8;
    u16* la1 = la0 + 512;
    u16* lb0 = Bs + wid * 1024 + lane * 8;
    u16* lb1 = lb0 + 512;

    f32x4 acc[4][4];
#pragma unroll
    for (int i = 0; i < 4; i++)
#pragma unroll
        for (int j = 0; j < 4; j++) acc[i][j] = (f32x4){0.f, 0.f, 0.f, 0.f};

    for (int k0 = 0; k0 < K; k0 += 32) {
        gl_lds16(Ag0 + k0, la0);
        gl_lds16(Ag1 + k0, la1);
        gl_lds16(Bg0 + k0, lb0);
        gl_lds16(Bg1 + k0, lb1);
        __syncthreads();   // drains vmcnt(0) then barrier
        bf16x8 af[4], bfr[4];
#pragma unroll
        for (int mb = 0; mb < 4; mb++) af[mb]  = *(const bf16x8*)&As[(wr + mb * 16 + n16) * 32 + q4 * 8];
#pragma unroll
        for (int nb = 0; nb < 4; nb++) bfr[nb] = *(const bf16x8*)&Bs[(wc + nb * 16 + n16) * 32 + q4 * 8];
#pragma unroll
        for (int mb = 0; mb < 4; mb++)
#pragma unroll
            for (int nb = 0; nb < 4; nb++)
                acc[mb][nb] = mfma_bf16(af[mb], bfr[nb], acc[mb][nb]);
        __syncthreads();   // all reads done before next overwrite
    }

#pragma unroll
    for (int mb = 0; mb < 4; mb++)
#pragma unroll
        for (int nb = 0; nb < 4; nb++)
#pragma unroll
            for (int r = 0; r < 4; r++) {
                long row = rowT + wr + mb * 16 + q4 * 4 + r;
                long col = colT + wc + nb * 16 + n16;
                if (F32OUT) ((float*)Cp)[row * N + col] = acc[mb][nb][r];
                else        ((u16*)Cp)[row * N + col]   = f2bf(acc[mb][nb][r]);
            }
}

// ---------------------------------------------------------------------------
// RMSNorm + interleaved RoPE in-place on bf16 qkv [8192][4096].
// q-heads additionally scaled by (1/sqrt(128))*log2(e), folding the softmax
// scale + exp2 conversion into Q (exact for softmax).
// ---------------------------------------------------------------------------
__global__ __launch_bounds__(256)
void rmsnorm_rope(u16* __restrict__ qkv, const float* __restrict__ cosT,
                  const float* __restrict__ sinT, const float* __restrict__ qg,
                  const float* __restrict__ kg) {
    const int w = blockIdx.x * 4 + (threadIdx.x >> 6);
    const int lane = threadIdx.x & 63;
    const int token = w / 24;
    const int hv = w - token * 24;            // 0..15 q-head, 16..23 k-head
    const long base = (long)token * 4096 + (hv < 16 ? hv * 128 : 2048 + (hv - 16) * 128);
    const float* g = (hv < 16) ? qg : kg;
    const int t = token & 2047;

    u32 pair = *(const u32*)(qkv + base + 2 * lane);
    float a0 = bf2f((u16)(pair & 0xffffu));
    float a1 = bf2f((u16)(pair >> 16));
    float ss = a0 * a0 + a1 * a1;
#pragma unroll
    for (int off = 32; off > 0; off >>= 1) ss += __shfl_xor(ss, off);
    float rs = rsqrtf(ss * (1.0f / 128.0f) + 1e-6f);
    float h0 = a0 * rs * g[2 * lane];
    float h1 = a1 * rs * g[2 * lane + 1];
    float2 cp = *(const float2*)(cosT + (long)t * 128 + 2 * lane);
    float2 sp = *(const float2*)(sinT + (long)t * 128 + 2 * lane);
    float o0 = h0 * cp.x - h1 * sp.x;
    float o1 = h1 * cp.y + h0 * sp.y;
    if (hv < 16) {
        const float QS = 0.08838834764831845f * 1.4426950408889634f;
        o0 *= QS; o1 *= QS;
    }
    *(u32*)(qkv + base + 2 * lane) = ((u32)f2bf(o0)) | (((u32)f2bf(o1)) << 16);
}

// ---------------------------------------------------------------------------
// Flash attention, transposed-scores, barrier-free.
// Grid (16, 64): x = 128-row Q tile, y = b*16+h. Wave owns 32 Q-rows (2 qb).
// Per 64-key tile: S^T = K·Q^T (keys on m-axis -> key-reduce = regs + 2 shfl),
// P^T packed to wave-private LDS as P[qrow][key] via ds_write_b64, PV from
// LDS A-frags + direct-global V^T B-frags. No __syncthreads anywhere.
// ---------------------------------------------------------------------------
__global__ __launch_bounds__(256)
void flash_attn(const u16* __restrict__ qkv, const u16* __restrict__ Vt,
                u16* __restrict__ attn) {
    __shared__ __align__(16) u16 Ps[4][32][72];   // wave-private slices, pad 64->72
    const int tid = threadIdx.x, wid = tid >> 6, lane = tid & 63;
    const int q4 = lane >> 4, n16 = lane & 15;
    const int b = blockIdx.y >> 4, h = blockIdx.y & 15;
    const int kvh = h >> 1;
    const long rowbase = (long)b * 2048;
    const long qbase = rowbase + (long)blockIdx.x * 128 + wid * 32;

    // Q B-frags (resident): Q[qrow = qbase+qb*16+n16][d = c*32+q4*8 ..]
    bf16x8 qf[2][4];
#pragma unroll
    for (int qb = 0; qb < 2; qb++) {
        const u16* p = qkv + (qbase + qb * 16 + n16) * 4096 + h * 128;
#pragma unroll
        for (int c = 0; c < 4; c++) qf[qb][c] = *(const bf16x8*)(p + c * 32 + q4 * 8);
    }

    f32x4 o[2][8];
#pragma unroll
    for (int i = 0; i < 2; i++)
#pragma unroll
        for (int j = 0; j < 8; j++) o[i][j] = (f32x4){0.f, 0.f, 0.f, 0.f};
    float m_i[2] = {-1e30f, -1e30f};
    float l_i[2] = {0.f, 0.f};

    const u16* Kbase = qkv + rowbase * 4096 + 2048 + kvh * 128;     // + t*4096 + d
    const u16* Vbase = Vt + ((long)(b * 8 + kvh) * 128) * 2048;     // + d*2048 + t

    for (int kt = 0; kt < 2048; kt += 64) {
        // ---- S^T = K Q^T : A-frag = K rows (direct global), B-frag = qf ----
        f32x4 s[2][4];
#pragma unroll
        for (int qb = 0; qb < 2; qb++)
#pragma unroll
            for (int kb = 0; kb < 4; kb++) s[qb][kb] = (f32x4){0.f, 0.f, 0.f, 0.f};
#pragma unroll
        for (int c = 0; c < 4; c++) {
            bf16x8 kf[4];
#pragma unroll
            for (int kb = 0; kb < 4; kb++)
                kf[kb] = *(const bf16x8*)(Kbase + (long)(kt + kb * 16 + n16) * 4096 + c * 32 + q4 * 8);
#pragma unroll
            for (int qb = 0; qb < 2; qb++)
#pragma unroll
                for (int kb = 0; kb < 4; kb++)
                    s[qb][kb] = mfma_bf16(kf[kb], qf[qb][c], s[qb][kb]);
        }

        // ---- online softmax (log2 domain; scale folded into Q) ----
#pragma unroll
        for (int qb = 0; qb < 2; qb++) {
            float mx = -1e30f;
#pragma unroll
            for (int kb = 0; kb < 4; kb++)
#pragma unroll
                for (int r = 0; r < 4; r++) mx = fmaxf(mx, s[qb][kb][r]);
            mx = fmaxf(mx, __shfl_xor(mx, 16));
            mx = fmaxf(mx, __shfl_xor(mx, 32));
            float mnew = fmaxf(m_i[qb], mx);
            float alpha = exp2f(m_i[qb] - mnew);
            m_i[qb] = mnew;
            float sum = 0.f;
            u32 pk[4][2];
#pragma unroll
            for (int kb = 0; kb < 4; kb++) {
                float p0 = exp2f(s[qb][kb][0] - mnew);
                float p1 = exp2f(s[qb][kb][1] - mnew);
                float p2 = exp2f(s[qb][kb][2] - mnew);
                float p3 = exp2f(s[qb][kb][3] - mnew);
                sum += (p0 + p1) + (p2 + p3);
                pk[kb][0] = packtrunc(p0, p1);
                pk[kb][1] = packtrunc(p2, p3);
            }
            sum += __shfl_xor(sum, 16);
            sum += __shfl_xor(sum, 32);
            l_i[qb] = l_i[qb] * alpha + sum;
            if (__any(alpha < 1.0f)) {          // rare after warm-up
                float a4[4];
#pragma unroll
                for (int r = 0; r < 4; r++)
                    a4[r] = __shfl(alpha, (lane & 48) | ((lane >> 4) * 4) | r);
#pragma unroll
                for (int nbh = 0; nbh < 8; nbh++)
#pragma unroll
                    for (int r = 0; r < 4; r++) o[qb][nbh][r] *= a4[r];
            }
            // P[qrow][key]: 4 contiguous keys per lane -> one 8B write per kb
#pragma unroll
            for (int kb = 0; kb < 4; kb++)
                *(uint2*)&Ps[wid][qb * 16 + n16][kb * 16 + q4 * 4] =
                    make_uint2(pk[kb][0], pk[kb][1]);
        }

        // ---- PV: A = P-frag (wave-private LDS), B = V^T-frag (direct global) ----
#pragma unroll
        for (int kc = 0; kc < 2; kc++) {
            bf16x8 vf[8];
#pragma unroll
            for (int nbh = 0; nbh < 8; nbh++)
                vf[nbh] = *(const bf16x8*)(Vbase + (long)(nbh * 16 + n16) * 2048 + kt + kc * 32 + q4 * 8);
#pragma unroll
            for (int qb = 0; qb < 2; qb++) {
                bf16x8 pf = *(const bf16x8*)&Ps[wid][qb * 16 + n16][kc * 32 + q4 * 8];
#pragma unroll
                for (int nbh = 0; nbh < 8; nbh++)
                    o[qb][nbh] = mfma_bf16(pf, vf[nbh], o[qb][nbh]);
            }
        }
    }

    // ---- epilogue: O /= l, write bf16 attn[8192][2048] ----
#pragma unroll
    for (int qb = 0; qb < 2; qb++) {
        float linv = 1.0f / l_i[qb];
        float l4[4];
#pragma unroll
        for (int r = 0; r < 4; r++)
            l4[r] = __shfl(linv, (lane & 48) | ((lane >> 4) * 4) | r);
#pragma unroll
        for (int r = 0; r < 4; r++) {
            u16* op = attn + (qbase + qb * 16 + q4 * 4 + r) * 2048 + h * 128 + n16;
#pragma unroll
            for (int nbh = 0; nbh < 8; nbh++)
                op[nbh * 16] = f2bf(o[qb][nbh][r] * l4[r]);
        }
    }
}

// ---------------------------------------------------------------------------
// ws layout (bytes), total 125.8 MB:
//   Bt_qkv / Vt  @ 0          16,777,216   (Vt overwrites Bt_qkv after gemm_qkv)
//   Bt_o         @ 16777216    8,388,608
//   xb / attn    @ 25165824   33,554,432   (attn overwrites xb after gemm_qkv)
//   qkv          @ 58720256   67,108,864
// ---------------------------------------------------------------------------
extern "C" void kernel_launch(void* const* d_in, const int* in_sizes, int n_in,
                              void* d_out, int out_size, void* d_ws, size_t ws_size,
                              hipStream_t stream) {
    const float* x    = (const float*)d_in[0];
    const float* cosT = (const float*)d_in[1];
    const float* sinT = (const float*)d_in[2];
    const float* Wq   = (const float*)d_in[3];
    const float* Wk   = (const float*)d_in[4];
    const float* Wv   = (const float*)d_in[5];
    const float* Wo   = (const float*)d_in[6];
    const float* qg   = (const float*)d_in[7];
    const float* kg   = (const float*)d_in[8];
    float* out = (float*)d_out;

    char* ws = (char*)d_ws;
    u16* Bt_qkv = (u16*)(ws);
    u16* Vt     = (u16*)(ws);              // reuses Bt_qkv after gemm_qkv
    u16* Bt_o   = (u16*)(ws + 16777216);
    u16* xb     = (u16*)(ws + 25165824);
    u16* attn   = (u16*)(ws + 25165824);   // reuses xb after gemm_qkv
    u16* qkv    = (u16*)(ws + 58720256);

    transpose_f2b<<<dim3(64, 64), 256, 0, stream>>>(Wq, Bt_qkv, 2048, 2048);
    transpose_f2b<<<dim3(32, 64), 256, 0, stream>>>(Wk, Bt_qkv + (size_t)2048 * 2048, 2048, 1024);
    transpose_f2b<<<dim3(32, 64), 256, 0, stream>>>(Wv, Bt_qkv + (size_t)3072 * 2048, 2048, 1024);
    transpose_f2b<<<dim3(64, 64), 256, 0, stream>>>(Wo, Bt_o, 2048, 2048);
    cast_f2b<<<dim3(8192), 256, 0, stream>>>(x, xb);

    gemm_bt_bf16<false><<<dim3(32, 64), 256, 0, stream>>>(xb, Bt_qkv, qkv, 8192, 4096, 2048);

    transpose_v<<<dim3(32, 256), 256, 0, stream>>>(qkv, Vt);
    rmsnorm_rope<<<dim3(49152), 256, 0, stream>>>(qkv, cosT, sinT, qg, kg);

    flash_attn<<<dim3(16, 64), 256, 0, stream>>>(qkv, Vt, attn);

    gemm_bt_bf16<true><<<dim3(16, 64), 256, 0, stream>>>(attn, Bt_o, out, 8192, 2048, 2048);
}